// Round 1
// baseline (584.884 us; speedup 1.0000x reference)
//
#include <hip/hip_runtime.h>
#include <hip/hip_bf16.h>

#define B_   8
#define SQ_  2048
#define SK_  2048
#define D_   1024
#define DV_  1024

typedef __bf16 bf16;
typedef __attribute__((ext_vector_type(4))) __bf16 bf16x4;
typedef __attribute__((ext_vector_type(8))) __bf16 bf16x8;
typedef __attribute__((ext_vector_type(4))) float  f32x4;

// ---------------------------------------------------------------------------
// K1: raw scaled scores  S = Q K^T / 32  into the weights region (unmasked).
// Blocks entirely above the causal diagonal / beyond qlen / beyond klen exit
// early; K2 overwrites every element so no masking or zero-fill needed here.
// 64x64 tile, BK=64, 4 waves each own a 16-row strip x 64 cols (4 MFMA tiles).
// ---------------------------------------------------------------------------
__global__ __launch_bounds__(256)
void scores_kernel(const float* __restrict__ Q, const float* __restrict__ K,
                   const int* __restrict__ qlens, const int* __restrict__ klens,
                   float* __restrict__ Wout)
{
    const int b  = blockIdx.z;
    const int q0 = blockIdx.y * 64;
    const int k0 = blockIdx.x * 64;
    if (k0 > q0 + 63) return;                    // fully above diagonal
    const int qlen = qlens[b], klen = klens[b];
    if (q0 >= qlen || k0 >= klen) return;        // fully masked rows/cols

    __shared__ __align__(16) bf16 Qs[64][72];    // +8 pad: rows stay 16B aligned
    __shared__ __align__(16) bf16 Ks[64][72];

    const int tid  = threadIdx.x;
    const int lane = tid & 63;
    const int w    = tid >> 6;                   // wave 0..3

    const float* Qb = Q + (size_t)b * SQ_ * D_;
    const float* Kb = K + (size_t)b * SK_ * D_;

    f32x4 acc[4] = {};                           // 4 col-tiles of 16x16

    for (int d0 = 0; d0 < D_; d0 += 64) {
        #pragma unroll
        for (int i = 0; i < 4; ++i) {
            int s   = tid + i * 256;             // 0..1023 float4 slots
            int row = s >> 4;
            int c4  = (s & 15) << 2;
            const float4 qv = *(const float4*)(Qb + (size_t)(q0 + row) * D_ + d0 + c4);
            const float4 kv = *(const float4*)(Kb + (size_t)(k0 + row) * D_ + d0 + c4);
            bf16x4 qb = { (bf16)qv.x, (bf16)qv.y, (bf16)qv.z, (bf16)qv.w };
            bf16x4 kb = { (bf16)kv.x, (bf16)kv.y, (bf16)kv.z, (bf16)kv.w };
            *(bf16x4*)&Qs[row][c4] = qb;
            *(bf16x4*)&Ks[row][c4] = kb;
        }
        __syncthreads();
        #pragma unroll
        for (int kk = 0; kk < 2; ++kk) {         // two K=32 chunks
            const int koff = kk * 32 + ((lane >> 4) << 3);
            bf16x8 a = *(const bf16x8*)&Qs[16 * w + (lane & 15)][koff];
            #pragma unroll
            for (int c = 0; c < 4; ++c) {
                bf16x8 bb = *(const bf16x8*)&Ks[16 * c + (lane & 15)][koff];
                acc[c] = __builtin_amdgcn_mfma_f32_16x16x32_bf16(a, bb, acc[c], 0, 0, 0);
            }
        }
        __syncthreads();
    }

    float* Wb = Wout + (size_t)b * SQ_ * SK_;
    const int rbase = q0 + 16 * w + ((lane >> 4) << 2);   // C/D: row=(lane>>4)*4+reg
    const int cbase = k0 + (lane & 15);                   //      col=lane&15
    #pragma unroll
    for (int c = 0; c < 4; ++c) {
        #pragma unroll
        for (int r = 0; r < 4; ++r) {
            Wb[(size_t)(rbase + r) * SK_ + (cbase + 16 * c)] = acc[c][r] * 0.03125f;
        }
    }
}

// ---------------------------------------------------------------------------
// K2: masked softmax, in place over the weights region. One block per (b,q)
// row; recomputes mask; masked entries (and fully-masked rows) -> exact 0.
// ---------------------------------------------------------------------------
__global__ __launch_bounds__(256)
void softmax_kernel(const int* __restrict__ qlens, const int* __restrict__ klens,
                    float* __restrict__ W)
{
    const int bq = blockIdx.x;          // b*SQ + q
    const int b  = bq >> 11;
    const int q  = bq & 2047;
    const int qlen = qlens[b], klen = klens[b];
    int kmax = 0;
    if (q < qlen) kmax = min(klen, q + 1);   // valid cols: k < klen && k <= q

    float* row = W + (size_t)bq * SK_;
    const int tid = threadIdx.x;

    float s[8];
    float m = -INFINITY;
    #pragma unroll
    for (int i = 0; i < 8; ++i) {
        int k = tid + i * 256;
        s[i] = (k < kmax) ? row[k] : -INFINITY;
        m = fmaxf(m, s[i]);
    }
    #pragma unroll
    for (int off = 32; off > 0; off >>= 1) m = fmaxf(m, __shfl_xor(m, off, 64));
    __shared__ float red[4];
    if ((tid & 63) == 0) red[tid >> 6] = m;
    __syncthreads();
    m = fmaxf(fmaxf(red[0], red[1]), fmaxf(red[2], red[3]));
    __syncthreads();

    float e[8];
    float sum = 0.f;
    #pragma unroll
    for (int i = 0; i < 8; ++i) {
        int k = tid + i * 256;
        e[i] = (k < kmax) ? __expf(s[i] - m) : 0.f;
        sum += e[i];
    }
    #pragma unroll
    for (int off = 32; off > 0; off >>= 1) sum += __shfl_xor(sum, off, 64);
    if ((tid & 63) == 0) red[tid >> 6] = sum;
    __syncthreads();
    sum = red[0] + red[1] + red[2] + red[3];

    const float inv = (sum > 0.f) ? (1.f / sum) : 0.f;   // fully-masked -> 0
    #pragma unroll
    for (int i = 0; i < 8; ++i) row[tid + i * 256] = e[i] * inv;
}

// ---------------------------------------------------------------------------
// K3: context = W @ V. W rows are exactly zero where masked, so k-loop is
// bounded by min(q0+64, ceil64(klen)) and invalid rows emit zeros for free.
// V is staged transposed into LDS (contraction dim is V's row index).
// ---------------------------------------------------------------------------
__global__ __launch_bounds__(256)
void context_kernel(const float* __restrict__ W, const float* __restrict__ V,
                    const int* __restrict__ klens, float* __restrict__ Out)
{
    const int b  = blockIdx.z;
    const int q0 = blockIdx.y * 64;
    const int n0 = blockIdx.x * 64;
    const int klen = klens[b];
    const int kend = min(q0 + 64, (klen + 63) & ~63);

    __shared__ __align__(16) bf16 Ws[64][72];
    __shared__ __align__(16) bf16 Vs[64][72];   // transposed: Vs[n][k]

    const int tid  = threadIdx.x;
    const int lane = tid & 63;
    const int w    = tid >> 6;

    const float* Wb = W + (size_t)b * SQ_ * SK_;
    const float* Vb = V + (size_t)b * SK_ * DV_;

    f32x4 acc[4] = {};

    for (int k0 = 0; k0 < kend; k0 += 64) {
        #pragma unroll
        for (int i = 0; i < 4; ++i) {
            int s   = tid + i * 256;
            int row = s >> 4;
            int c4  = (s & 15) << 2;
            const float4 wv = *(const float4*)(Wb + (size_t)(q0 + row) * SK_ + k0 + c4);
            bf16x4 wb = { (bf16)wv.x, (bf16)wv.y, (bf16)wv.z, (bf16)wv.w };
            *(bf16x4*)&Ws[row][c4] = wb;
            const float4 vv = *(const float4*)(Vb + (size_t)(k0 + row) * DV_ + n0 + c4);
            Vs[c4 + 0][row] = (bf16)vv.x;       // scatter-transpose
            Vs[c4 + 1][row] = (bf16)vv.y;
            Vs[c4 + 2][row] = (bf16)vv.z;
            Vs[c4 + 3][row] = (bf16)vv.w;
        }
        __syncthreads();
        #pragma unroll
        for (int kk = 0; kk < 2; ++kk) {
            const int koff = kk * 32 + ((lane >> 4) << 3);
            bf16x8 a = *(const bf16x8*)&Ws[16 * w + (lane & 15)][koff];
            #pragma unroll
            for (int c = 0; c < 4; ++c) {
                bf16x8 bb = *(const bf16x8*)&Vs[16 * c + (lane & 15)][koff];
                acc[c] = __builtin_amdgcn_mfma_f32_16x16x32_bf16(a, bb, acc[c], 0, 0, 0);
            }
        }
        __syncthreads();
    }

    float* Ob = Out + (size_t)b * SQ_ * DV_;
    const int rbase = q0 + 16 * w + ((lane >> 4) << 2);
    const int cbase = n0 + (lane & 15);
    #pragma unroll
    for (int c = 0; c < 4; ++c) {
        #pragma unroll
        for (int r = 0; r < 4; ++r) {
            Ob[(size_t)(rbase + r) * DV_ + (cbase + 16 * c)] = acc[c][r];
        }
    }
}

extern "C" void kernel_launch(void* const* d_in, const int* in_sizes, int n_in,
                              void* d_out, int out_size, void* d_ws, size_t ws_size,
                              hipStream_t stream) {
    (void)in_sizes; (void)n_in; (void)out_size; (void)d_ws; (void)ws_size;
    const float* Q     = (const float*)d_in[0];
    const float* K     = (const float*)d_in[1];
    const float* V     = (const float*)d_in[2];
    const int*   qlens = (const int*)d_in[3];
    const int*   klens = (const int*)d_in[4];

    float* ctx = (float*)d_out;                          // (B,SQ,DV) first
    float* wts = ctx + (size_t)B_ * SQ_ * DV_;           // then (B,SQ,SK)

    dim3 g1(SK_ / 64, SQ_ / 64, B_);
    scores_kernel<<<g1, 256, 0, stream>>>(Q, K, qlens, klens, wts);

    softmax_kernel<<<dim3(B_ * SQ_), 256, 0, stream>>>(qlens, klens, wts);

    dim3 g3(DV_ / 64, SQ_ / 64, B_);
    context_kernel<<<g3, 256, 0, stream>>>(wts, V, klens, ctx);
}

// Round 2
// 509.493 us; speedup vs baseline: 1.1480x; 1.1480x over previous
//
#include <hip/hip_runtime.h>
#include <hip/hip_bf16.h>

#define B_   8
#define SQ_  2048
#define SK_  2048
#define D_   1024
#define DV_  1024

typedef __bf16 bf16;
typedef __attribute__((ext_vector_type(4))) __bf16 bf16x4;
typedef __attribute__((ext_vector_type(8))) __bf16 bf16x8;
typedef __attribute__((ext_vector_type(4))) float  f32x4;

// ---------------------------------------------------------------------------
// K1: raw scaled scores S = Q K^T / 32 into the weights region (unmasked).
// 128x128 tile, BK=64, 4 waves (2x2), each wave owns 64x64 = 4x4 MFMA tiles.
// Causal/len-skipped blocks are never read by K2/K3 after masking logic.
// ---------------------------------------------------------------------------
__global__ __launch_bounds__(256)
void scores_kernel(const float* __restrict__ Q, const float* __restrict__ K,
                   const int* __restrict__ qlens, const int* __restrict__ klens,
                   float* __restrict__ Wout)
{
    const int b  = blockIdx.z;
    const int q0 = blockIdx.y * 128;
    const int k0 = blockIdx.x * 128;
    if (k0 > q0 + 127) return;                   // fully above causal diagonal
    const int qlen = qlens[b], klen = klens[b];
    if (q0 >= qlen || k0 >= klen) return;        // fully masked

    __shared__ __align__(16) bf16 Qs[128][72];
    __shared__ __align__(16) bf16 Ks[128][72];

    const int tid  = threadIdx.x;
    const int lane = tid & 63;
    const int w    = tid >> 6;                   // wave 0..3
    const int wq   = w >> 1, wk = w & 1;         // 2x2 wave grid

    const float* Qb = Q + (size_t)b * SQ_ * D_;
    const float* Kb = K + (size_t)b * SK_ * D_;

    f32x4 acc[4][4] = {};                        // [m][n] 16x16 tiles

    for (int d0 = 0; d0 < D_; d0 += 64) {
        #pragma unroll
        for (int i = 0; i < 8; ++i) {
            int s   = tid + i * 256;             // 2048 float4 slots
            int row = s >> 4;
            int c4  = (s & 15) << 2;
            const float4 qv = *(const float4*)(Qb + (size_t)(q0 + row) * D_ + d0 + c4);
            const float4 kv = *(const float4*)(Kb + (size_t)(k0 + row) * D_ + d0 + c4);
            bf16x4 qb = { (bf16)qv.x, (bf16)qv.y, (bf16)qv.z, (bf16)qv.w };
            bf16x4 kb = { (bf16)kv.x, (bf16)kv.y, (bf16)kv.z, (bf16)kv.w };
            *(bf16x4*)&Qs[row][c4] = qb;
            *(bf16x4*)&Ks[row][c4] = kb;
        }
        __syncthreads();
        #pragma unroll
        for (int kk = 0; kk < 2; ++kk) {         // two K=32 chunks
            const int koff = kk * 32 + ((lane >> 4) << 3);
            bf16x8 a[4], bb[4];
            #pragma unroll
            for (int m = 0; m < 4; ++m)
                a[m] = *(const bf16x8*)&Qs[64 * wq + 16 * m + (lane & 15)][koff];
            #pragma unroll
            for (int n = 0; n < 4; ++n)
                bb[n] = *(const bf16x8*)&Ks[64 * wk + 16 * n + (lane & 15)][koff];
            #pragma unroll
            for (int m = 0; m < 4; ++m)
                #pragma unroll
                for (int n = 0; n < 4; ++n)
                    acc[m][n] = __builtin_amdgcn_mfma_f32_16x16x32_bf16(a[m], bb[n], acc[m][n], 0, 0, 0);
        }
        __syncthreads();
    }

    float* Wb = Wout + (size_t)b * SQ_ * SK_;
    const int rb = q0 + 64 * wq + ((lane >> 4) << 2);  // + 16m + r
    const int cb = k0 + 64 * wk + (lane & 15);         // + 16n
    #pragma unroll
    for (int m = 0; m < 4; ++m)
        #pragma unroll
        for (int n = 0; n < 4; ++n)
            #pragma unroll
            for (int r = 0; r < 4; ++r)
                Wb[(size_t)(rb + 16 * m + r) * SK_ + (cb + 16 * n)] = acc[m][n][r] * 0.03125f;
}

// ---------------------------------------------------------------------------
// K2: masked softmax in place. One block per (b,q) row; float4 vectorized.
// Masked entries (and fully-masked rows) -> exact 0.
// ---------------------------------------------------------------------------
__global__ __launch_bounds__(256)
void softmax_kernel(const int* __restrict__ qlens, const int* __restrict__ klens,
                    float* __restrict__ W)
{
    const int bq = blockIdx.x;          // b*SQ + q
    const int b  = bq >> 11;
    const int q  = bq & 2047;
    const int qlen = qlens[b], klen = klens[b];
    int kmax = 0;
    if (q < qlen) kmax = min(klen, q + 1);   // valid cols: k < klen && k <= q

    float4* row = (float4*)(W + (size_t)bq * SK_);
    const int tid = threadIdx.x;

    float4 x[2];
    float m = -INFINITY;
    #pragma unroll
    for (int i = 0; i < 2; ++i) {
        int v4 = tid + i * 256;              // float4 index
        x[i] = row[v4];
        int kb = v4 << 2;
        float* xe = (float*)&x[i];
        #pragma unroll
        for (int e = 0; e < 4; ++e) {
            if (kb + e >= kmax) xe[e] = -INFINITY;
            m = fmaxf(m, xe[e]);
        }
    }
    #pragma unroll
    for (int off = 32; off > 0; off >>= 1) m = fmaxf(m, __shfl_xor(m, off, 64));
    __shared__ float red[4];
    if ((tid & 63) == 0) red[tid >> 6] = m;
    __syncthreads();
    m = fmaxf(fmaxf(red[0], red[1]), fmaxf(red[2], red[3]));
    __syncthreads();

    float sum = 0.f;
    #pragma unroll
    for (int i = 0; i < 2; ++i) {
        float* xe = (float*)&x[i];
        #pragma unroll
        for (int e = 0; e < 4; ++e) {
            float ev = (xe[e] == -INFINITY) ? 0.f : __expf(xe[e] - m);
            xe[e] = ev;
            sum += ev;
        }
    }
    #pragma unroll
    for (int off = 32; off > 0; off >>= 1) sum += __shfl_xor(sum, off, 64);
    if ((tid & 63) == 0) red[tid >> 6] = sum;
    __syncthreads();
    sum = red[0] + red[1] + red[2] + red[3];

    const float inv = (sum > 0.f) ? (1.f / sum) : 0.f;   // fully-masked -> 0
    #pragma unroll
    for (int i = 0; i < 2; ++i) {
        float* xe = (float*)&x[i];
        float4 o = { xe[0] * inv, xe[1] * inv, xe[2] * inv, xe[3] * inv };
        row[tid + i * 256] = o;
    }
}

// ---------------------------------------------------------------------------
// K3: context = W @ V. 128x128 tile, BK=64. W rows are exactly zero where
// masked, so the k-loop is bounded by min(q0+128, ceil64(klen)).
// V staged transposed via lane-coalesced scalar loads + contiguous b128
// LDS writes (no column-scatter -> no 16-way bank conflicts).
// ---------------------------------------------------------------------------
__global__ __launch_bounds__(256)
void context_kernel(const float* __restrict__ W, const float* __restrict__ V,
                    const int* __restrict__ klens, float* __restrict__ Out)
{
    const int b  = blockIdx.z;
    const int q0 = blockIdx.y * 128;
    const int n0 = blockIdx.x * 128;
    const int klen = klens[b];
    const int kend = min(q0 + 128, (klen + 63) & ~63);

    __shared__ __align__(16) bf16 Ws[128][72];
    __shared__ __align__(16) bf16 Vs[128][72];   // transposed: Vs[n][k]

    const int tid  = threadIdx.x;
    const int lane = tid & 63;
    const int w    = tid >> 6;
    const int wq   = w >> 1, wn = w & 1;

    const float* Wb = W + (size_t)b * SQ_ * SK_;
    const float* Vb = V + (size_t)b * SK_ * DV_;

    f32x4 acc[4][4] = {};

    for (int kk0 = 0; kk0 < kend; kk0 += 64) {
        // A-tile: W 128q x 64k, coalesced float4 along k
        #pragma unroll
        for (int i = 0; i < 8; ++i) {
            int s   = tid + i * 256;
            int row = s >> 4;
            int c4  = (s & 15) << 2;
            const float4 wv = *(const float4*)(Wb + (size_t)(q0 + row) * SK_ + kk0 + c4);
            bf16x4 wb = { (bf16)wv.x, (bf16)wv.y, (bf16)wv.z, (bf16)wv.w };
            *(bf16x4*)&Ws[row][c4] = wb;
        }
        // B-tile: V 64k x 128n -> Vs[n][k]; lane-coalesced reads along n,
        // contiguous b128 write along k.
        #pragma unroll
        for (int i = 0; i < 4; ++i) {
            int t   = tid + i * 256;             // 1024 tasks: 128n x 8 octets
            int n   = t & 127;
            int oct = t >> 7;                    // 0..7
            float v[8];
            #pragma unroll
            for (int j = 0; j < 8; ++j)
                v[j] = Vb[(size_t)(kk0 + oct * 8 + j) * DV_ + n0 + n];
            bf16x8 vb = { (bf16)v[0], (bf16)v[1], (bf16)v[2], (bf16)v[3],
                          (bf16)v[4], (bf16)v[5], (bf16)v[6], (bf16)v[7] };
            *(bf16x8*)&Vs[n][oct * 8] = vb;
        }
        __syncthreads();
        #pragma unroll
        for (int kk = 0; kk < 2; ++kk) {
            const int koff = kk * 32 + ((lane >> 4) << 3);
            bf16x8 a[4], bb[4];
            #pragma unroll
            for (int m = 0; m < 4; ++m)
                a[m] = *(const bf16x8*)&Ws[64 * wq + 16 * m + (lane & 15)][koff];
            #pragma unroll
            for (int n = 0; n < 4; ++n)
                bb[n] = *(const bf16x8*)&Vs[64 * wn + 16 * n + (lane & 15)][koff];
            #pragma unroll
            for (int m = 0; m < 4; ++m)
                #pragma unroll
                for (int n = 0; n < 4; ++n)
                    acc[m][n] = __builtin_amdgcn_mfma_f32_16x16x32_bf16(a[m], bb[n], acc[m][n], 0, 0, 0);
        }
        __syncthreads();
    }

    float* Ob = Out + (size_t)b * SQ_ * DV_;
    const int rb = q0 + 64 * wq + ((lane >> 4) << 2);
    const int cb = n0 + 64 * wn + (lane & 15);
    #pragma unroll
    for (int m = 0; m < 4; ++m)
        #pragma unroll
        for (int n = 0; n < 4; ++n)
            #pragma unroll
            for (int r = 0; r < 4; ++r)
                Ob[(size_t)(rb + 16 * m + r) * DV_ + (cb + 16 * n)] = acc[m][n][r];
}

extern "C" void kernel_launch(void* const* d_in, const int* in_sizes, int n_in,
                              void* d_out, int out_size, void* d_ws, size_t ws_size,
                              hipStream_t stream) {
    (void)in_sizes; (void)n_in; (void)out_size; (void)d_ws; (void)ws_size;
    const float* Q     = (const float*)d_in[0];
    const float* K     = (const float*)d_in[1];
    const float* V     = (const float*)d_in[2];
    const int*   qlens = (const int*)d_in[3];
    const int*   klens = (const int*)d_in[4];

    float* ctx = (float*)d_out;                          // (B,SQ,DV) first
    float* wts = ctx + (size_t)B_ * SQ_ * DV_;           // then (B,SQ,SK)

    dim3 g1(SK_ / 128, SQ_ / 128, B_);
    scores_kernel<<<g1, 256, 0, stream>>>(Q, K, qlens, klens, wts);

    softmax_kernel<<<dim3(B_ * SQ_), 256, 0, stream>>>(qlens, klens, wts);

    dim3 g3(DV_ / 128, SQ_ / 128, B_);
    context_kernel<<<g3, 256, 0, stream>>>(wts, V, klens, ctx);
}

// Round 3
// 472.301 us; speedup vs baseline: 1.2384x; 1.0787x over previous
//
#include <hip/hip_runtime.h>
#include <hip/hip_bf16.h>

#define B_   8
#define SQ_  2048
#define SK_  2048
#define D_   1024
#define DV_  1024

typedef __bf16 bf16;
typedef __attribute__((ext_vector_type(4))) __bf16 bf16x4;
typedef __attribute__((ext_vector_type(8))) __bf16 bf16x8;
typedef __attribute__((ext_vector_type(4))) float  f32x4;

// ---------------------------------------------------------------------------
// K1: raw scaled scores S = Q K^T / 32 into the weights region (unmasked).
// 128x128 tile, BK=64, 512 threads = 8 waves (4q x 2k), wave owns 32x64.
// Double-buffered LDS + reg prefetch: at ~1.4 blocks/CU (mask kills most
// blocks) there is no implicit wave overlap, so the load latency must be
// hidden explicitly inside the block.
// ---------------------------------------------------------------------------
__global__ __launch_bounds__(512, 4)
void scores_kernel(const float* __restrict__ Q, const float* __restrict__ K,
                   const int* __restrict__ qlens, const int* __restrict__ klens,
                   float* __restrict__ Wout)
{
    const int b  = blockIdx.z;
    const int q0 = blockIdx.y * 128;
    const int k0 = blockIdx.x * 128;
    if (k0 > q0 + 127) return;                   // fully above causal diagonal
    const int qlen = qlens[b], klen = klens[b];
    if (q0 >= qlen || k0 >= klen) return;        // fully masked

    __shared__ __align__(16) bf16 Qs[2][128][72];
    __shared__ __align__(16) bf16 Ks[2][128][72];

    const int tid  = threadIdx.x;
    const int lane = tid & 63;
    const int w    = tid >> 6;                   // wave 0..7
    const int wq   = w >> 1, wk = w & 1;         // 4x2 wave grid

    const float* Qb = Q + (size_t)b * SQ_ * D_;
    const float* Kb = K + (size_t)b * SK_ * D_;

    float4 qreg[4], kreg[4];
    int srow[4], sc4[4];
    #pragma unroll
    for (int i = 0; i < 4; ++i) {
        int s = tid + i * 512;                   // 2048 float4 slots per array
        srow[i] = s >> 4;
        sc4[i]  = (s & 15) << 2;
    }

    auto load_tile = [&](int d0) {
        #pragma unroll
        for (int i = 0; i < 4; ++i) {
            qreg[i] = *(const float4*)(Qb + (size_t)(q0 + srow[i]) * D_ + d0 + sc4[i]);
            kreg[i] = *(const float4*)(Kb + (size_t)(k0 + srow[i]) * D_ + d0 + sc4[i]);
        }
    };
    auto store_tile = [&](int buf) {
        #pragma unroll
        for (int i = 0; i < 4; ++i) {
            bf16x4 qb = { (bf16)qreg[i].x, (bf16)qreg[i].y, (bf16)qreg[i].z, (bf16)qreg[i].w };
            bf16x4 kb = { (bf16)kreg[i].x, (bf16)kreg[i].y, (bf16)kreg[i].z, (bf16)kreg[i].w };
            *(bf16x4*)&Qs[buf][srow[i]][sc4[i]] = qb;
            *(bf16x4*)&Ks[buf][srow[i]][sc4[i]] = kb;
        }
    };

    f32x4 acc[2][4] = {};                        // wave tile 32x64

    load_tile(0);
    store_tile(0);
    __syncthreads();

    for (int it = 0; it < 16; ++it) {
        const int cur = it & 1;
        if (it < 15) load_tile((it + 1) * 64);   // prefetch next into regs
        #pragma unroll
        for (int kk = 0; kk < 2; ++kk) {
            const int koff = kk * 32 + ((lane >> 4) << 3);
            bf16x8 a[2], bb[4];
            #pragma unroll
            for (int m = 0; m < 2; ++m)
                a[m] = *(const bf16x8*)&Qs[cur][32 * wq + 16 * m + (lane & 15)][koff];
            #pragma unroll
            for (int n = 0; n < 4; ++n)
                bb[n] = *(const bf16x8*)&Ks[cur][64 * wk + 16 * n + (lane & 15)][koff];
            #pragma unroll
            for (int m = 0; m < 2; ++m)
                #pragma unroll
                for (int n = 0; n < 4; ++n)
                    acc[m][n] = __builtin_amdgcn_mfma_f32_16x16x32_bf16(a[m], bb[n], acc[m][n], 0, 0, 0);
        }
        if (it < 15) store_tile(1 - cur);        // write next buffer
        __syncthreads();
    }

    float* Wb = Wout + (size_t)b * SQ_ * SK_;
    const int rb = q0 + 32 * wq + ((lane >> 4) << 2);  // + 16m + r
    const int cb = k0 + 64 * wk + (lane & 15);         // + 16n
    #pragma unroll
    for (int m = 0; m < 2; ++m)
        #pragma unroll
        for (int n = 0; n < 4; ++n)
            #pragma unroll
            for (int r = 0; r < 4; ++r)
                Wb[(size_t)(rb + 16 * m + r) * SK_ + (cb + 16 * n)] = acc[m][n][r] * 0.03125f;
}

// ---------------------------------------------------------------------------
// K2: masked softmax in place. One block per (b,q) row. Reads bounded by
// kmax (saves ~100 MB); writes full row (zeros beyond kmax / masked rows).
// ---------------------------------------------------------------------------
__global__ __launch_bounds__(256)
void softmax_kernel(const int* __restrict__ qlens, const int* __restrict__ klens,
                    float* __restrict__ W)
{
    const int bq = blockIdx.x;          // b*SQ + q
    const int b  = bq >> 11;
    const int q  = bq & 2047;
    const int qlen = qlens[b], klen = klens[b];
    int kmax = 0;
    if (q < qlen) kmax = min(klen, q + 1);   // valid cols: k < klen && k <= q

    float4* row = (float4*)(W + (size_t)bq * SK_);
    const int tid = threadIdx.x;

    float4 x[2];
    float m = -INFINITY;
    #pragma unroll
    for (int i = 0; i < 2; ++i) {
        int v4 = tid + i * 256;              // float4 index
        int kb = v4 << 2;
        if (kb < kmax) x[i] = row[v4];       // only read live region
        else           x[i] = make_float4(-INFINITY, -INFINITY, -INFINITY, -INFINITY);
        float* xe = (float*)&x[i];
        #pragma unroll
        for (int e = 0; e < 4; ++e) {
            if (kb + e >= kmax) xe[e] = -INFINITY;
            m = fmaxf(m, xe[e]);
        }
    }
    #pragma unroll
    for (int off = 32; off > 0; off >>= 1) m = fmaxf(m, __shfl_xor(m, off, 64));
    __shared__ float red[4];
    if ((tid & 63) == 0) red[tid >> 6] = m;
    __syncthreads();
    m = fmaxf(fmaxf(red[0], red[1]), fmaxf(red[2], red[3]));
    __syncthreads();

    float sum = 0.f;
    #pragma unroll
    for (int i = 0; i < 2; ++i) {
        float* xe = (float*)&x[i];
        #pragma unroll
        for (int e = 0; e < 4; ++e) {
            float ev = (xe[e] == -INFINITY) ? 0.f : __expf(xe[e] - m);
            xe[e] = ev;
            sum += ev;
        }
    }
    #pragma unroll
    for (int off = 32; off > 0; off >>= 1) sum += __shfl_xor(sum, off, 64);
    if ((tid & 63) == 0) red[tid >> 6] = sum;
    __syncthreads();
    sum = red[0] + red[1] + red[2] + red[3];

    const float inv = (sum > 0.f) ? (1.f / sum) : 0.f;   // fully-masked -> 0
    #pragma unroll
    for (int i = 0; i < 2; ++i) {
        float* xe = (float*)&x[i];
        float4 o = { xe[0] * inv, xe[1] * inv, xe[2] * inv, xe[3] * inv };
        row[tid + i * 256] = o;
    }
}

// ---------------------------------------------------------------------------
// K3: context = W @ V. 128x128 tile, BK=64, 512 threads = 8 waves (4q x 2n),
// double-buffered LDS + reg prefetch. W rows are exactly zero where masked,
// so the k-loop is bounded by min(q0+128, ceil64(klen)).
// ---------------------------------------------------------------------------
__global__ __launch_bounds__(512, 4)
void context_kernel(const float* __restrict__ W, const float* __restrict__ V,
                    const int* __restrict__ klens, float* __restrict__ Out)
{
    const int b  = blockIdx.z;
    const int q0 = blockIdx.y * 128;
    const int n0 = blockIdx.x * 128;
    const int klen = klens[b];
    const int kend = min(q0 + 128, (klen + 63) & ~63);
    const int nk   = kend >> 6;                  // >= 1 always

    __shared__ __align__(16) bf16 Ws[2][128][72];
    __shared__ __align__(16) bf16 Vs[2][128][72];   // transposed: Vs[.][n][k]

    const int tid  = threadIdx.x;
    const int lane = tid & 63;
    const int w    = tid >> 6;
    const int wq   = w >> 1, wn = w & 1;

    const float* Wb = W + (size_t)b * SQ_ * SK_;
    const float* Vb = V + (size_t)b * SK_ * DV_;

    float4 wreg[4];
    float  vreg[2][8];
    int srow[4], sc4[4], vn[2], voct[2];
    #pragma unroll
    for (int i = 0; i < 4; ++i) {
        int s = tid + i * 512;
        srow[i] = s >> 4;
        sc4[i]  = (s & 15) << 2;
    }
    #pragma unroll
    for (int i = 0; i < 2; ++i) {
        int t = tid + i * 512;                   // 1024 tasks: 128n x 8 octets
        vn[i]   = t & 127;
        voct[i] = t >> 7;
    }

    auto load_tile = [&](int kk0) {
        #pragma unroll
        for (int i = 0; i < 4; ++i)
            wreg[i] = *(const float4*)(Wb + (size_t)(q0 + srow[i]) * SK_ + kk0 + sc4[i]);
        #pragma unroll
        for (int i = 0; i < 2; ++i)
            #pragma unroll
            for (int j = 0; j < 8; ++j)
                vreg[i][j] = Vb[(size_t)(kk0 + voct[i] * 8 + j) * DV_ + n0 + vn[i]];
    };
    auto store_tile = [&](int buf) {
        #pragma unroll
        for (int i = 0; i < 4; ++i) {
            bf16x4 wb = { (bf16)wreg[i].x, (bf16)wreg[i].y, (bf16)wreg[i].z, (bf16)wreg[i].w };
            *(bf16x4*)&Ws[buf][srow[i]][sc4[i]] = wb;
        }
        #pragma unroll
        for (int i = 0; i < 2; ++i) {
            bf16x8 vb = { (bf16)vreg[i][0], (bf16)vreg[i][1], (bf16)vreg[i][2], (bf16)vreg[i][3],
                          (bf16)vreg[i][4], (bf16)vreg[i][5], (bf16)vreg[i][6], (bf16)vreg[i][7] };
            *(bf16x8*)&Vs[buf][vn[i]][voct[i] * 8] = vb;
        }
    };

    f32x4 acc[2][4] = {};

    load_tile(0);
    store_tile(0);
    __syncthreads();

    for (int it = 0; it < nk; ++it) {
        const int cur = it & 1;
        if (it + 1 < nk) load_tile((it + 1) * 64);
        #pragma unroll
        for (int kk = 0; kk < 2; ++kk) {
            const int koff = kk * 32 + ((lane >> 4) << 3);
            bf16x8 a[2], bb[4];
            #pragma unroll
            for (int m = 0; m < 2; ++m)
                a[m] = *(const bf16x8*)&Ws[cur][32 * wq + 16 * m + (lane & 15)][koff];
            #pragma unroll
            for (int n = 0; n < 4; ++n)
                bb[n] = *(const bf16x8*)&Vs[cur][64 * wn + 16 * n + (lane & 15)][koff];
            #pragma unroll
            for (int m = 0; m < 2; ++m)
                #pragma unroll
                for (int n = 0; n < 4; ++n)
                    acc[m][n] = __builtin_amdgcn_mfma_f32_16x16x32_bf16(a[m], bb[n], acc[m][n], 0, 0, 0);
        }
        if (it + 1 < nk) store_tile(1 - cur);
        __syncthreads();
    }

    float* Ob = Out + (size_t)b * SQ_ * DV_;
    const int rb = q0 + 32 * wq + ((lane >> 4) << 2);
    const int cb = n0 + 64 * wn + (lane & 15);
    #pragma unroll
    for (int m = 0; m < 2; ++m)
        #pragma unroll
        for (int n = 0; n < 4; ++n)
            #pragma unroll
            for (int r = 0; r < 4; ++r)
                Ob[(size_t)(rb + 16 * m + r) * DV_ + (cb + 16 * n)] = acc[m][n][r];
}

extern "C" void kernel_launch(void* const* d_in, const int* in_sizes, int n_in,
                              void* d_out, int out_size, void* d_ws, size_t ws_size,
                              hipStream_t stream) {
    (void)in_sizes; (void)n_in; (void)out_size; (void)d_ws; (void)ws_size;
    const float* Q     = (const float*)d_in[0];
    const float* K     = (const float*)d_in[1];
    const float* V     = (const float*)d_in[2];
    const int*   qlens = (const int*)d_in[3];
    const int*   klens = (const int*)d_in[4];

    float* ctx = (float*)d_out;                          // (B,SQ,DV) first
    float* wts = ctx + (size_t)B_ * SQ_ * DV_;           // then (B,SQ,SK)

    dim3 g1(SK_ / 128, SQ_ / 128, B_);
    scores_kernel<<<g1, 512, 0, stream>>>(Q, K, qlens, klens, wts);

    softmax_kernel<<<dim3(B_ * SQ_), 256, 0, stream>>>(qlens, klens, wts);

    dim3 g3(DV_ / 128, SQ_ / 128, B_);
    context_kernel<<<g3, 512, 0, stream>>>(wts, V, klens, ctx);
}